// Round 8
// baseline (241.457 us; speedup 1.0000x reference)
//
#include <hip/hip_runtime.h>
#include <hip/hip_bf16.h>

#define B_ 4
#define C_IN 128
#define C_OUT 256
#define N_IN 40962
#define N_OUT 10242
#define NPAD 10272          // N_OUT padded to multiple of 32 (zero-filled)
#define EPS_ 1e-5f
#define CNT_ ((float)(B_ * N_OUT))

typedef __attribute__((ext_vector_type(8))) short bf16x8;
typedef __attribute__((ext_vector_type(4))) float f32x4;

__device__ __forceinline__ float bf2f(unsigned short u) {
    union { unsigned int i; float f; } c;
    c.i = ((unsigned int)u) << 16;
    return c.f;
}
__device__ __forceinline__ unsigned short f2bf(float f) {
    union { float f; unsigned int i; } c;
    c.f = f;
    unsigned int r = c.i + 0x7FFFu + ((c.i >> 16) & 1u);  // RNE
    return (unsigned short)(r >> 16);
}

// ---------------------------------------------------------------------------
// K1: transpose x[b][k][i] (f32) -> xT[b][i][k] (bf16); trailing blocks do
//     the W f32->bf16 conversion.
// ---------------------------------------------------------------------------
#define IBLK 64
#define NB_I ((N_IN + IBLK - 1) / IBLK)   // 641
#define WCONV_BLKS ((C_OUT * C_IN) / 256) // 128

__global__ __launch_bounds__(256) void k_transpose(const float* __restrict__ x,
                                                   unsigned short* __restrict__ xT,
                                                   const float* __restrict__ W,
                                                   unsigned short* __restrict__ Wb) {
    if (blockIdx.x >= B_ * NB_I) {
        int i = (blockIdx.x - B_ * NB_I) * 256 + threadIdx.x;
        Wb[i] = f2bf(W[i]);
        return;
    }
    __shared__ float tile[IBLK][C_IN + 1];
    int b  = blockIdx.x / NB_I;
    int ib = blockIdx.x % NB_I;
    int i0 = ib * IBLK;
    int t = threadIdx.x;
    int lane = t & 63;
    int q = t >> 6;

    const float* xb = x + (size_t)b * C_IN * N_IN;
    int i = i0 + lane;
    if (i < N_IN) {
#pragma unroll
        for (int p = 0; p < 32; p++) {
            int k = p * 4 + q;
            tile[lane][k] = xb[(size_t)k * N_IN + i];
        }
    }
    __syncthreads();

    unsigned short* xTb = xT + (size_t)b * N_IN * C_IN;
#pragma unroll
    for (int p = 0; p < 16; p++) {
        int il = p * 4 + q;
        int gi = i0 + il;
        if (gi < N_IN) {
            int k2 = lane * 2;
            float a = tile[il][k2];
            float c = tile[il][k2 + 1];
            unsigned int pk = (unsigned int)f2bf(a) | ((unsigned int)f2bf(c) << 16);
            *reinterpret_cast<unsigned int*>(xTb + (size_t)gi * C_IN + k2) = pk;
        }
    }
}

// ---------------------------------------------------------------------------
// K2: gather-mean -> g[b][n][ch] AND gT[b][ch][n] (n padded to NPAD, zeros)
// ---------------------------------------------------------------------------
#define GNB 16
#define NB_G (NPAD / GNB)  // 642 (covers pad columns with zeros)

__global__ __launch_bounds__(256) void k_gather(const unsigned short* __restrict__ xT,
                                                const int* __restrict__ idx,
                                                unsigned short* __restrict__ g,
                                                unsigned short* __restrict__ gT) {
    __shared__ unsigned short tl[GNB][C_IN + 8];  // [row][ch], stride 136
    int b  = blockIdx.x / NB_G;
    int nb = blockIdx.x % NB_G;
    int n0 = nb * GNB;
    int t = threadIdx.x;
    int grp = t >> 4, c = t & 15;

    const unsigned short* xTb = xT + (size_t)b * N_IN * C_IN;
    int n = n0 + grp;
    float s[8];
#pragma unroll
    for (int e = 0; e < 8; e++) s[e] = 0.f;
    if (n < N_OUT) {
        const int* ip = idx + 7 * n;
#pragma unroll
        for (int j = 0; j < 7; j++) {
            int id = ip[j];
            bf16x8 v = *reinterpret_cast<const bf16x8*>(xTb + (size_t)id * C_IN + c * 8);
#pragma unroll
            for (int e = 0; e < 8; e++) s[e] += bf2f((unsigned short)v[e]);
        }
    }
    const float inv7 = 1.0f / 7.0f;
    bf16x8 r;
#pragma unroll
    for (int e = 0; e < 8; e++) r[e] = (short)f2bf(s[e] * inv7);
    *reinterpret_cast<bf16x8*>(&tl[grp][c * 8]) = r;
    if (n < N_OUT)
        *reinterpret_cast<bf16x8*>(g + ((size_t)b * N_OUT + n) * C_IN + c * 8) = r;
    __syncthreads();

    // transposed write: thread t -> channel t>>1, n-half t&1
    int ch = t >> 1, h = t & 1;
    bf16x8 v;
#pragma unroll
    for (int r8 = 0; r8 < 8; r8++) v[r8] = (short)tl[h * 8 + r8][ch];
    *reinterpret_cast<bf16x8*>(gT + (size_t)b * C_IN * NPAD + (size_t)ch * NPAD + n0 + h * 8) = v;
}

// ---------------------------------------------------------------------------
// K3: SYRK over gT: Mp[blk] = partial of M = sum_n g_n g_n^T (+ ones-row -> s_g)
// 64 blocks, 4 waves; wave w owns m-tiles {2w,2w+1} x 8 n-tiles. K=32 samples.
// ---------------------------------------------------------------------------
#define STEPS_PB (NPAD / 32)        // 321
#define TOT_STEPS (B_ * STEPS_PB)   // 1284
#define SYRK_BLKS 64
#define SLAB (130 * 128)            // per-block partial: rows 0..127 = M, 128 = s_g

__global__ __launch_bounds__(256) void k_syrk(const unsigned short* __restrict__ gT,
                                              float* __restrict__ Mp) {
    int t = threadIdx.x;
    int w = t >> 6, l = t & 63, lr = l & 15, lg = l >> 4;

    f32x4 acc[2][8];
#pragma unroll
    for (int mi = 0; mi < 2; mi++)
#pragma unroll
        for (int ni = 0; ni < 8; ni++) acc[mi][ni] = (f32x4)(0.0f);
    f32x4 acco[8];
#pragma unroll
    for (int ni = 0; ni < 8; ni++) acco[ni] = (f32x4)(0.0f);

    bf16x8 afro;
#pragma unroll
    for (int e = 0; e < 8; e++) afro[e] = (lr == 0) ? (short)0x3F80 : (short)0;

    for (int s = blockIdx.x; s < TOT_STEPS; s += SYRK_BLKS) {
        int bb = s / STEPS_PB;
        int st = s % STEPS_PB;
        const unsigned short* base = gT + (size_t)bb * C_IN * NPAD + st * 32 + lg * 8;
        bf16x8 bf[8];
#pragma unroll
        for (int ni = 0; ni < 8; ni++)
            bf[ni] = *reinterpret_cast<const bf16x8*>(base + (size_t)(ni * 16 + lr) * NPAD);
#pragma unroll
        for (int ni = 0; ni < 8; ni++) {
#pragma unroll
            for (int mi = 0; mi < 2; mi++)
                acc[mi][ni] = __builtin_amdgcn_mfma_f32_16x16x32_bf16(bf[2 * w + mi], bf[ni],
                                                                     acc[mi][ni], 0, 0, 0);
            if (w == 0)
                acco[ni] = __builtin_amdgcn_mfma_f32_16x16x32_bf16(afro, bf[ni],
                                                                  acco[ni], 0, 0, 0);
        }
    }

    float* slab = Mp + (size_t)blockIdx.x * SLAB;
#pragma unroll
    for (int mi = 0; mi < 2; mi++) {
#pragma unroll
        for (int ni = 0; ni < 8; ni++) {
#pragma unroll
            for (int r = 0; r < 4; r++) {
                int i = (2 * w + mi) * 16 + lg * 4 + r;
                int j = ni * 16 + lr;
                slab[i * 128 + j] = acc[mi][ni][r];
            }
        }
    }
    if (w == 0 && lg == 0) {
#pragma unroll
        for (int ni = 0; ni < 8; ni++)
            slab[128 * 128 + ni * 16 + lr] = acco[ni][0];
    }
}

// ---------------------------------------------------------------------------
// K4: reduce 64 partial slabs -> Msum[129*128]
// ---------------------------------------------------------------------------
#define ME (129 * 128)  // 16512

__global__ __launch_bounds__(256) void k_redM(const float* __restrict__ Mp,
                                              float* __restrict__ Msum) {
    int e = blockIdx.x * 256 + threadIdx.x;
    if (e >= ME) return;
    float a = 0.f;
#pragma unroll 8
    for (int p = 0; p < SYRK_BLKS; p++) a += Mp[(size_t)p * SLAB + e];
    Msum[e] = a;
}

// ---------------------------------------------------------------------------
// K5: per-channel scale/shift from quadratic form:
//   var_o = w^T M w / cnt - mz^2,  mz = w . s_g / cnt
//   ss[o] = gamma*rsqrt(var+eps); ss[C_OUT+o] = beta - ss[o]*mz
// 32 blocks x 8 channels; 32 lanes per channel.
// ---------------------------------------------------------------------------
__global__ __launch_bounds__(256) void k_scale(const float* __restrict__ Msum,
                                               const unsigned short* __restrict__ Wb,
                                               const float* __restrict__ gamma,
                                               const float* __restrict__ beta,
                                               float* __restrict__ ss) {
    __shared__ float wvs[8][132];
    int t = threadIdx.x;
    int chl = t >> 5, lane = t & 31;
    int o = blockIdx.x * 8 + chl;

    // stage this block's 8 W rows (bf16 -> f32)
#pragma unroll
    for (int k = 0; k < 4; k++)
        wvs[chl][lane * 4 + k] = bf2f(Wb[(size_t)o * C_IN + lane * 4 + k]);
    __syncthreads();

    float qf = 0.f;
    const float* wv = wvs[chl];
#pragma unroll 4
    for (int i = 0; i < C_IN; i++) {
        f32x4 m4 = *reinterpret_cast<const f32x4*>(Msum + i * 128 + lane * 4);
        float part = m4[0] * wv[lane * 4] + m4[1] * wv[lane * 4 + 1] +
                     m4[2] * wv[lane * 4 + 2] + m4[3] * wv[lane * 4 + 3];
        qf += wv[i] * part;
    }
    f32x4 sg4 = *reinterpret_cast<const f32x4*>(Msum + 128 * 128 + lane * 4);
    float mzp = sg4[0] * wv[lane * 4] + sg4[1] * wv[lane * 4 + 1] +
                sg4[2] * wv[lane * 4 + 2] + sg4[3] * wv[lane * 4 + 3];
#pragma unroll
    for (int d = 1; d < 32; d <<= 1) {
        qf  += __shfl_xor(qf, d, 64);
        mzp += __shfl_xor(mzp, d, 64);
    }
    if (lane == 0) {
        float mz = mzp / CNT_;
        float var = qf / CNT_ - mz * mz;
        float a = gamma[o] * rsqrtf(var + EPS_);
        ss[o] = a;
        ss[C_OUT + o] = beta[o] - a * mz;
    }
}

// ---------------------------------------------------------------------------
// K6: GEMM (z = W g, no bias) + out = a*z + shift   (shift folds bias+beta)
// ---------------------------------------------------------------------------
#define NT2 64
#define NB_N2 ((N_OUT + NT2 - 1) / NT2)  // 161

__global__ __launch_bounds__(256, 2) void k_final_gemm(const unsigned short* __restrict__ g,
                                                       const unsigned short* __restrict__ Wb,
                                                       const float* __restrict__ ss,
                                                       float* __restrict__ out) {
    int b  = blockIdx.x / NB_N2;
    int nb = blockIdx.x % NB_N2;
    int n0 = nb * NT2;
    int t = threadIdx.x;
    int w = t >> 6, l = t & 63, lr = l & 15, lg = l >> 4;
    int wbase = w * 64;

    bf16x8 afrag[4][4];
#pragma unroll
    for (int mt = 0; mt < 4; mt++)
#pragma unroll
        for (int ks = 0; ks < 4; ks++)
            afrag[mt][ks] = *reinterpret_cast<const bf16x8*>(
                Wb + (size_t)(wbase + mt * 16 + lr) * C_IN + ks * 32 + lg * 8);

    f32x4 acc[4][4];
#pragma unroll
    for (int mt = 0; mt < 4; mt++)
#pragma unroll
        for (int nt = 0; nt < 4; nt++) acc[mt][nt] = (f32x4)(0.0f);

    const unsigned short* gb = g + (size_t)b * N_OUT * C_IN;
#pragma unroll
    for (int nt = 0; nt < 4; nt++) {
        int n = n0 + nt * 16 + lr;
        const unsigned short* gr = gb + (size_t)((n < N_OUT) ? n : 0) * C_IN;
#pragma unroll
        for (int ks = 0; ks < 4; ks++) {
            bf16x8 bfr = *reinterpret_cast<const bf16x8*>(gr + ks * 32 + lg * 8);
#pragma unroll
            for (int mt = 0; mt < 4; mt++)
                acc[mt][nt] = __builtin_amdgcn_mfma_f32_16x16x32_bf16(afrag[mt][ks], bfr,
                                                                     acc[mt][nt], 0, 0, 0);
        }
    }

    float* ob = out + (size_t)b * C_OUT * N_OUT;
#pragma unroll
    for (int mt = 0; mt < 4; mt++) {
#pragma unroll
        for (int j = 0; j < 4; j++) {
            int o = wbase + mt * 16 + lg * 4 + j;
            float a = ss[o];
            float sh = ss[C_OUT + o];
#pragma unroll
            for (int nt = 0; nt < 4; nt++) {
                int n = n0 + nt * 16 + lr;
                if (n < N_OUT) ob[(size_t)o * N_OUT + n] = a * acc[mt][nt][j] + sh;
            }
        }
    }
}

// ---------------------------------------------------------------------------
extern "C" void kernel_launch(void* const* d_in, const int* in_sizes, int n_in,
                              void* d_out, int out_size, void* d_ws, size_t ws_size,
                              hipStream_t stream) {
    const float* x     = (const float*)d_in[0];
    const int*   idx   = (const int*)d_in[1];
    const float* W     = (const float*)d_in[2];
    const float* bias  = (const float*)d_in[3];  // folded into mz? no: bias only affects mean; z excludes bias, shift = beta - a*mz handles it
    const float* gamma = (const float*)d_in[4];
    const float* beta  = (const float*)d_in[5];
    float* out = (float*)d_out;
    (void)bias;

    const size_t xt_bytes = (size_t)B_ * N_IN * C_IN * sizeof(unsigned short);    // 41,945,088
    const size_t g_bytes  = (size_t)B_ * N_OUT * C_IN * sizeof(unsigned short);   // 10,487,808
    const size_t gt_bytes = (size_t)B_ * C_IN * NPAD * sizeof(unsigned short);    // 10,518,528
    const size_t wb_bytes = (size_t)C_OUT * C_IN * sizeof(unsigned short);        // 65,536
    char* p = (char*)d_ws;
    unsigned short* xT = (unsigned short*)p;               p += xt_bytes;
    unsigned short* gg = (unsigned short*)p;               p += g_bytes;
    unsigned short* gT = (unsigned short*)p;               p += gt_bytes;
    unsigned short* Wb = (unsigned short*)p;               p += wb_bytes;
    float* Mp   = (float*)p;                               p += (size_t)SYRK_BLKS * SLAB * sizeof(float);  // 4.26 MB
    float* Msum = (float*)p;                               p += (size_t)ME * sizeof(float);
    float* ss   = (float*)p;

    k_transpose<<<B_ * NB_I + WCONV_BLKS, 256, 0, stream>>>(x, xT, W, Wb);
    k_gather<<<B_ * NB_G, 256, 0, stream>>>(xT, idx, gg, gT);
    k_syrk<<<SYRK_BLKS, 256, 0, stream>>>(gT, Mp);
    k_redM<<<(ME + 255) / 256, 256, 0, stream>>>(Mp, Msum);
    k_scale<<<C_OUT / 8, 256, 0, stream>>>(Msum, Wb, gamma, beta, ss);
    k_final_gemm<<<B_ * NB_N2, 256, 0, stream>>>(gg, Wb, ss, out);
}

// Round 9
// 88.406 us; speedup vs baseline: 2.7312x; 2.7312x over previous
//
#include <hip/hip_runtime.h>
#include <hip/hip_bf16.h>

#define B_ 4
#define C_IN 128
#define C_OUT 256
#define N_IN 40962
#define N_OUT 10242
#define EPS_ 1e-5f
#define CNT_ ((float)(B_ * N_OUT))

typedef __attribute__((ext_vector_type(8))) short bf16x8;
typedef __attribute__((ext_vector_type(4))) float f32x4;

__device__ __forceinline__ float bf2f(unsigned short u) {
    union { unsigned int i; float f; } c;
    c.i = ((unsigned int)u) << 16;
    return c.f;
}
__device__ __forceinline__ unsigned short f2bf(float f) {
    union { float f; unsigned int i; } c;
    c.f = f;
    unsigned int r = c.i + 0x7FFFu + ((c.i >> 16) & 1u);  // RNE
    return (unsigned short)(r >> 16);
}

// ---------------------------------------------------------------------------
// K1: transpose x[b][k][i] (f32) -> xT[b][i][k] (bf16); trailing blocks do
//     the W f32->bf16 conversion.
// ---------------------------------------------------------------------------
#define IBLK 64
#define NB_I ((N_IN + IBLK - 1) / IBLK)   // 641
#define WCONV_BLKS ((C_OUT * C_IN) / 256) // 128

__global__ __launch_bounds__(256) void k_transpose(const float* __restrict__ x,
                                                   unsigned short* __restrict__ xT,
                                                   const float* __restrict__ W,
                                                   unsigned short* __restrict__ Wb) {
    if (blockIdx.x >= B_ * NB_I) {
        int i = (blockIdx.x - B_ * NB_I) * 256 + threadIdx.x;
        Wb[i] = f2bf(W[i]);
        return;
    }
    __shared__ float tile[IBLK][C_IN + 1];
    int b  = blockIdx.x / NB_I;
    int ib = blockIdx.x % NB_I;
    int i0 = ib * IBLK;
    int t = threadIdx.x;
    int lane = t & 63;
    int q = t >> 6;

    const float* xb = x + (size_t)b * C_IN * N_IN;
    int i = i0 + lane;
    if (i < N_IN) {
#pragma unroll
        for (int p = 0; p < 32; p++) {
            int k = p * 4 + q;
            tile[lane][k] = xb[(size_t)k * N_IN + i];
        }
    }
    __syncthreads();

    unsigned short* xTb = xT + (size_t)b * N_IN * C_IN;
#pragma unroll
    for (int p = 0; p < 16; p++) {
        int il = p * 4 + q;
        int gi = i0 + il;
        if (gi < N_IN) {
            int k2 = lane * 2;
            float a = tile[il][k2];
            float c = tile[il][k2 + 1];
            unsigned int pk = (unsigned int)f2bf(a) | ((unsigned int)f2bf(c) << 16);
            *reinterpret_cast<unsigned int*>(xTb + (size_t)gi * C_IN + k2) = pk;
        }
    }
}

// ---------------------------------------------------------------------------
// K2: gather-mean: g[b][n][k] = mean_j xT[b][idx[7n+j]][k]  (bf16 out)
// 16 threads per n; 2564 blocks for max TLP on the random L3 reads.
// ---------------------------------------------------------------------------
#define GNB 16
#define NB_G ((N_OUT + GNB - 1) / GNB)  // 641

__global__ __launch_bounds__(256) void k_gather(const unsigned short* __restrict__ xT,
                                                const int* __restrict__ idx,
                                                unsigned short* __restrict__ g) {
    int b  = blockIdx.x / NB_G;
    int nb = blockIdx.x % NB_G;
    int t = threadIdx.x;
    int n = nb * GNB + (t >> 4);
    int c = t & 15;
    if (n >= N_OUT) return;

    const unsigned short* xTb = xT + (size_t)b * N_IN * C_IN;
    const int* ip = idx + 7 * n;
    float s[8];
#pragma unroll
    for (int e = 0; e < 8; e++) s[e] = 0.f;
#pragma unroll
    for (int j = 0; j < 7; j++) {
        int id = ip[j];
        bf16x8 v = *reinterpret_cast<const bf16x8*>(xTb + (size_t)id * C_IN + c * 8);
#pragma unroll
        for (int e = 0; e < 8; e++) s[e] += bf2f((unsigned short)v[e]);
    }
    const float inv7 = 1.0f / 7.0f;
    bf16x8 r;
#pragma unroll
    for (int e = 0; e < 8; e++) r[e] = (short)f2bf(s[e] * inv7);
    *reinterpret_cast<bf16x8*>(g + ((size_t)b * N_OUT + n) * C_IN + c * 8) = r;
}

// ---------------------------------------------------------------------------
// GEMM tiling: 64-n tile per block, wave w owns 64 channels.
// ---------------------------------------------------------------------------
#define NT2 64
#define NB_N2 ((N_OUT + NT2 - 1) / NT2)  // 161
#define NBLK_GS (B_ * NB_N2)             // 644

// K3: GEMM -> per-block per-channel partials (no atomics)
__global__ __launch_bounds__(256, 2) void k_stats_gemm(const unsigned short* __restrict__ g,
                                                       const unsigned short* __restrict__ Wb,
                                                       const float* __restrict__ bias,
                                                       float* __restrict__ psum) {
    int bid = blockIdx.x;
    int b  = bid / NB_N2;
    int nb = bid % NB_N2;
    int n0 = nb * NT2;
    int t = threadIdx.x;
    int w = t >> 6, l = t & 63, lr = l & 15, lg = l >> 4;
    int wbase = w * 64;

    bf16x8 afrag[4][4];
#pragma unroll
    for (int mt = 0; mt < 4; mt++)
#pragma unroll
        for (int ks = 0; ks < 4; ks++)
            afrag[mt][ks] = *reinterpret_cast<const bf16x8*>(
                Wb + (size_t)(wbase + mt * 16 + lr) * C_IN + ks * 32 + lg * 8);

    f32x4 acc[4][4];
#pragma unroll
    for (int mt = 0; mt < 4; mt++)
#pragma unroll
        for (int nt = 0; nt < 4; nt++) acc[mt][nt] = (f32x4)(0.0f);

    const unsigned short* gb = g + (size_t)b * N_OUT * C_IN;
#pragma unroll
    for (int nt = 0; nt < 4; nt++) {
        int n = n0 + nt * 16 + lr;
        const unsigned short* gr = gb + (size_t)((n < N_OUT) ? n : 0) * C_IN;
#pragma unroll
        for (int ks = 0; ks < 4; ks++) {
            bf16x8 bfr = *reinterpret_cast<const bf16x8*>(gr + ks * 32 + lg * 8);
#pragma unroll
            for (int mt = 0; mt < 4; mt++)
                acc[mt][nt] = __builtin_amdgcn_mfma_f32_16x16x32_bf16(afrag[mt][ks], bfr,
                                                                     acc[mt][nt], 0, 0, 0);
        }
    }

    float ps1[16], ps2[16];
#pragma unroll
    for (int m = 0; m < 16; m++) { ps1[m] = 0.f; ps2[m] = 0.f; }
#pragma unroll
    for (int mt = 0; mt < 4; mt++) {
#pragma unroll
        for (int j = 0; j < 4; j++) {
            int o = wbase + mt * 16 + lg * 4 + j;
            float bv = bias[o];
#pragma unroll
            for (int nt = 0; nt < 4; nt++) {
                int n = n0 + nt * 16 + lr;
                if (n < N_OUT) {
                    float v = acc[mt][nt][j] + bv;
                    ps1[mt * 4 + j] += v;
                    ps2[mt * 4 + j] += v * v;
                }
            }
        }
    }

    __shared__ float red[2][C_OUT];
#pragma unroll
    for (int m = 0; m < 16; m++) {
        float a = ps1[m], cc = ps2[m];
#pragma unroll
        for (int d = 1; d < 16; d <<= 1) {
            a  += __shfl_xor(a, d, 64);
            cc += __shfl_xor(cc, d, 64);
        }
        if (lr == 0) {
            int mt = m >> 2, j = m & 3;
            int o = wbase + mt * 16 + lg * 4 + j;
            red[0][o] = a;
            red[1][o] = cc;
        }
    }
    __syncthreads();
    float* pb = psum + (size_t)bid * 2 * C_OUT;
    pb[t] = red[0][t];
    pb[C_OUT + t] = red[1][t];
}

// ---------------------------------------------------------------------------
// K4: merged reduce + finalize. 64 blocks x 4 waves; wave owns channel o,
// lanes stride the 644 psum rows, shuffle-reduce, lane 0 -> scale/shift.
// ---------------------------------------------------------------------------
__global__ __launch_bounds__(256) void k_stats_final(const float* __restrict__ psum,
                                                     const float* __restrict__ bias,
                                                     const float* __restrict__ gamma,
                                                     const float* __restrict__ beta,
                                                     float* __restrict__ ss) {
    int t = threadIdx.x;
    int w = t >> 6, l = t & 63;
    int o = blockIdx.x * 4 + w;  // 64 blocks * 4 waves = 256 channels
    float s1 = 0.f, s2 = 0.f;
    for (int i = l; i < NBLK_GS; i += 64) {
        const float* pb = psum + (size_t)i * 2 * C_OUT;
        s1 += pb[o];
        s2 += pb[C_OUT + o];
    }
#pragma unroll
    for (int d = 1; d < 64; d <<= 1) {
        s1 += __shfl_xor(s1, d, 64);
        s2 += __shfl_xor(s2, d, 64);
    }
    if (l == 0) {
        float mean = s1 / CNT_;
        float var = s2 / CNT_ - mean * mean;
        float a = gamma[o] * rsqrtf(var + EPS_);
        ss[o] = a;
        ss[C_OUT + o] = a * bias[o] + beta[o] - a * mean;
    }
}

// ---------------------------------------------------------------------------
// K5: GEMM + normalize + write out
// ---------------------------------------------------------------------------
__global__ __launch_bounds__(256, 2) void k_final_gemm(const unsigned short* __restrict__ g,
                                                       const unsigned short* __restrict__ Wb,
                                                       const float* __restrict__ ss,
                                                       float* __restrict__ out) {
    int b  = blockIdx.x / NB_N2;
    int nb = blockIdx.x % NB_N2;
    int n0 = nb * NT2;
    int t = threadIdx.x;
    int w = t >> 6, l = t & 63, lr = l & 15, lg = l >> 4;
    int wbase = w * 64;

    bf16x8 afrag[4][4];
#pragma unroll
    for (int mt = 0; mt < 4; mt++)
#pragma unroll
        for (int ks = 0; ks < 4; ks++)
            afrag[mt][ks] = *reinterpret_cast<const bf16x8*>(
                Wb + (size_t)(wbase + mt * 16 + lr) * C_IN + ks * 32 + lg * 8);

    f32x4 acc[4][4];
#pragma unroll
    for (int mt = 0; mt < 4; mt++)
#pragma unroll
        for (int nt = 0; nt < 4; nt++) acc[mt][nt] = (f32x4)(0.0f);

    const unsigned short* gb = g + (size_t)b * N_OUT * C_IN;
#pragma unroll
    for (int nt = 0; nt < 4; nt++) {
        int n = n0 + nt * 16 + lr;
        const unsigned short* gr = gb + (size_t)((n < N_OUT) ? n : 0) * C_IN;
#pragma unroll
        for (int ks = 0; ks < 4; ks++) {
            bf16x8 bfr = *reinterpret_cast<const bf16x8*>(gr + ks * 32 + lg * 8);
#pragma unroll
            for (int mt = 0; mt < 4; mt++)
                acc[mt][nt] = __builtin_amdgcn_mfma_f32_16x16x32_bf16(afrag[mt][ks], bfr,
                                                                     acc[mt][nt], 0, 0, 0);
        }
    }

    float* ob = out + (size_t)b * C_OUT * N_OUT;
#pragma unroll
    for (int mt = 0; mt < 4; mt++) {
#pragma unroll
        for (int j = 0; j < 4; j++) {
            int o = wbase + mt * 16 + lg * 4 + j;
            float a = ss[o];
            float sh = ss[C_OUT + o];
#pragma unroll
            for (int nt = 0; nt < 4; nt++) {
                int n = n0 + nt * 16 + lr;
                if (n < N_OUT) ob[(size_t)o * N_OUT + n] = a * acc[mt][nt][j] + sh;
            }
        }
    }
}

// ---------------------------------------------------------------------------
extern "C" void kernel_launch(void* const* d_in, const int* in_sizes, int n_in,
                              void* d_out, int out_size, void* d_ws, size_t ws_size,
                              hipStream_t stream) {
    const float* x     = (const float*)d_in[0];
    const int*   idx   = (const int*)d_in[1];
    const float* W     = (const float*)d_in[2];
    const float* bias  = (const float*)d_in[3];
    const float* gamma = (const float*)d_in[4];
    const float* beta  = (const float*)d_in[5];
    float* out = (float*)d_out;

    const size_t xt_bytes = (size_t)B_ * N_IN * C_IN * sizeof(unsigned short);   // 41,945,088
    const size_t g_bytes  = (size_t)B_ * N_OUT * C_IN * sizeof(unsigned short);  // 10,487,808
    const size_t wb_bytes = (size_t)C_OUT * C_IN * sizeof(unsigned short);       // 65,536
    unsigned short* xT = (unsigned short*)d_ws;
    unsigned short* gg = (unsigned short*)((char*)d_ws + xt_bytes);
    unsigned short* Wb = (unsigned short*)((char*)d_ws + xt_bytes + g_bytes);
    float* psum = (float*)((char*)d_ws + xt_bytes + g_bytes + wb_bytes);         // 644*512*4 = 1.32 MB
    float* ss   = psum + (size_t)NBLK_GS * 2 * C_OUT;

    k_transpose<<<B_ * NB_I + WCONV_BLKS, 256, 0, stream>>>(x, xT, W, Wb);
    k_gather<<<B_ * NB_G, 256, 0, stream>>>(xT, idx, gg);
    k_stats_gemm<<<NBLK_GS, 256, 0, stream>>>(gg, Wb, bias, psum);
    k_stats_final<<<64, 256, 0, stream>>>(psum, bias, gamma, beta, ss);
    k_final_gemm<<<B_ * NB_N2, 256, 0, stream>>>(gg, Wb, ss, out);
}

// Round 10
// 84.448 us; speedup vs baseline: 2.8592x; 1.0469x over previous
//
#include <hip/hip_runtime.h>
#include <hip/hip_bf16.h>

#define B_ 4
#define C_IN 128
#define C_OUT 256
#define N_IN 40962
#define N_OUT 10242
#define EPS_ 1e-5f
#define CNT_ ((float)(B_ * N_OUT))

typedef __attribute__((ext_vector_type(8))) short bf16x8;
typedef __attribute__((ext_vector_type(4))) float f32x4;

__device__ __forceinline__ float bf2f(unsigned short u) {
    union { unsigned int i; float f; } c;
    c.i = ((unsigned int)u) << 16;
    return c.f;
}
__device__ __forceinline__ unsigned short f2bf(float f) {
    union { float f; unsigned int i; } c;
    c.f = f;
    unsigned int r = c.i + 0x7FFFu + ((c.i >> 16) & 1u);  // RNE
    return (unsigned short)(r >> 16);
}

// ---------------------------------------------------------------------------
// K1: transpose x[b][k][i] (f32) -> xT[b][i][k] (bf16); trailing blocks do
//     the W f32->bf16 conversion. (bank-clean: write (i+k)%32, read 2-way)
// ---------------------------------------------------------------------------
#define IBLK 64
#define NB_I ((N_IN + IBLK - 1) / IBLK)   // 641
#define WCONV_BLKS ((C_OUT * C_IN) / 256) // 128

__global__ __launch_bounds__(256) void k_transpose(const float* __restrict__ x,
                                                   unsigned short* __restrict__ xT,
                                                   const float* __restrict__ W,
                                                   unsigned short* __restrict__ Wb) {
    if (blockIdx.x >= B_ * NB_I) {
        int i = (blockIdx.x - B_ * NB_I) * 256 + threadIdx.x;
        Wb[i] = f2bf(W[i]);
        return;
    }
    __shared__ float tile[IBLK][C_IN + 1];
    int b  = blockIdx.x / NB_I;
    int ib = blockIdx.x % NB_I;
    int i0 = ib * IBLK;
    int t = threadIdx.x;
    int lane = t & 63;
    int q = t >> 6;

    const float* xb = x + (size_t)b * C_IN * N_IN;
    int i = i0 + lane;
    if (i < N_IN) {
#pragma unroll
        for (int p = 0; p < 32; p++) {
            int k = p * 4 + q;
            tile[lane][k] = xb[(size_t)k * N_IN + i];
        }
    }
    __syncthreads();

    unsigned short* xTb = xT + (size_t)b * N_IN * C_IN;
#pragma unroll
    for (int p = 0; p < 16; p++) {
        int il = p * 4 + q;
        int gi = i0 + il;
        if (gi < N_IN) {
            int k2 = lane * 2;
            float a = tile[il][k2];
            float c = tile[il][k2 + 1];
            unsigned int pk = (unsigned int)f2bf(a) | ((unsigned int)f2bf(c) << 16);
            *reinterpret_cast<unsigned int*>(xTb + (size_t)gi * C_IN + k2) = pk;
        }
    }
}

// ---------------------------------------------------------------------------
// K2: gather-mean: g[b][n][k] = mean_j xT[b][idx[7n+j]][k]  (bf16 out)
// 16 threads per n; 2564 blocks for max TLP on the random L3 reads.
// ---------------------------------------------------------------------------
#define GNB 16
#define NB_G ((N_OUT + GNB - 1) / GNB)  // 641

__global__ __launch_bounds__(256) void k_gather(const unsigned short* __restrict__ xT,
                                                const int* __restrict__ idx,
                                                unsigned short* __restrict__ g) {
    int b  = blockIdx.x / NB_G;
    int nb = blockIdx.x % NB_G;
    int t = threadIdx.x;
    int n = nb * GNB + (t >> 4);
    int c = t & 15;
    if (n >= N_OUT) return;

    const unsigned short* xTb = xT + (size_t)b * N_IN * C_IN;
    const int* ip = idx + 7 * n;
    float s[8];
#pragma unroll
    for (int e = 0; e < 8; e++) s[e] = 0.f;
#pragma unroll
    for (int j = 0; j < 7; j++) {
        int id = ip[j];
        bf16x8 v = *reinterpret_cast<const bf16x8*>(xTb + (size_t)id * C_IN + c * 8);
#pragma unroll
        for (int e = 0; e < 8; e++) s[e] += bf2f((unsigned short)v[e]);
    }
    const float inv7 = 1.0f / 7.0f;
    bf16x8 r;
#pragma unroll
    for (int e = 0; e < 8; e++) r[e] = (short)f2bf(s[e] * inv7);
    *reinterpret_cast<bf16x8*>(g + ((size_t)b * N_OUT + n) * C_IN + c * 8) = r;
}

// ---------------------------------------------------------------------------
// GEMM tiling: 128-n tile per block processed as 2x 64-n halves reusing the
// same acc registers (afrag/Wb loaded once per block, epilogue amortized).
// ---------------------------------------------------------------------------
#define NT2 128
#define NB_N2 ((N_OUT + NT2 - 1) / NT2)  // 81
#define NBLK_GS (B_ * NB_N2)             // 324

// K3: GEMM -> per-block per-channel partials of z=Wg (bias folded out; var is
// bias-invariant, mean corrected in k_stats_final).
__global__ __launch_bounds__(256, 2) void k_stats_gemm(const unsigned short* __restrict__ g,
                                                       const unsigned short* __restrict__ Wb,
                                                       float* __restrict__ psum) {
    int bid = blockIdx.x;
    int b  = bid / NB_N2;
    int nb = bid % NB_N2;
    int t = threadIdx.x;
    int w = t >> 6, l = t & 63, lr = l & 15, lg = l >> 4;
    int wbase = w * 64;

    bf16x8 afrag[4][4];
#pragma unroll
    for (int mt = 0; mt < 4; mt++)
#pragma unroll
        for (int ks = 0; ks < 4; ks++)
            afrag[mt][ks] = *reinterpret_cast<const bf16x8*>(
                Wb + (size_t)(wbase + mt * 16 + lr) * C_IN + ks * 32 + lg * 8);

    const unsigned short* gb = g + (size_t)b * N_OUT * C_IN;
    float ps1[16], ps2[16];
#pragma unroll
    for (int m = 0; m < 16; m++) { ps1[m] = 0.f; ps2[m] = 0.f; }

    for (int h = 0; h < 2; h++) {
        int n0 = nb * NT2 + h * 64;
        f32x4 acc[4][4];
#pragma unroll
        for (int mt = 0; mt < 4; mt++)
#pragma unroll
            for (int nt = 0; nt < 4; nt++) acc[mt][nt] = (f32x4)(0.0f);

#pragma unroll
        for (int nt = 0; nt < 4; nt++) {
            int n = n0 + nt * 16 + lr;
            const unsigned short* gr = gb + (size_t)((n < N_OUT) ? n : 0) * C_IN;
#pragma unroll
            for (int ks = 0; ks < 4; ks++) {
                bf16x8 bfr = *reinterpret_cast<const bf16x8*>(gr + ks * 32 + lg * 8);
#pragma unroll
                for (int mt = 0; mt < 4; mt++)
                    acc[mt][nt] = __builtin_amdgcn_mfma_f32_16x16x32_bf16(afrag[mt][ks], bfr,
                                                                         acc[mt][nt], 0, 0, 0);
            }
        }
#pragma unroll
        for (int mt = 0; mt < 4; mt++) {
#pragma unroll
            for (int j = 0; j < 4; j++) {
#pragma unroll
                for (int nt = 0; nt < 4; nt++) {
                    int n = n0 + nt * 16 + lr;
                    if (n < N_OUT) {
                        float v = acc[mt][nt][j];
                        ps1[mt * 4 + j] += v;
                        ps2[mt * 4 + j] += v * v;
                    }
                }
            }
        }
    }

    __shared__ float red[2][C_OUT];
#pragma unroll
    for (int m = 0; m < 16; m++) {
        float a = ps1[m], cc = ps2[m];
#pragma unroll
        for (int d = 1; d < 16; d <<= 1) {
            a  += __shfl_xor(a, d, 64);
            cc += __shfl_xor(cc, d, 64);
        }
        if (lr == 0) {
            int mt = m >> 2, j = m & 3;
            int o = wbase + mt * 16 + lg * 4 + j;
            red[0][o] = a;
            red[1][o] = cc;
        }
    }
    __syncthreads();
    float* pb = psum + (size_t)bid * 2 * C_OUT;
    pb[t] = red[0][t];
    pb[C_OUT + t] = red[1][t];
}

// ---------------------------------------------------------------------------
// K4: merged reduce + finalize. 64 blocks x 4 waves; wave owns channel o.
//   mean_y = sum(z)/cnt + bias;  var = sum(z^2)/cnt - (sum(z)/cnt)^2
// ---------------------------------------------------------------------------
__global__ __launch_bounds__(256) void k_stats_final(const float* __restrict__ psum,
                                                     const float* __restrict__ bias,
                                                     const float* __restrict__ gamma,
                                                     const float* __restrict__ beta,
                                                     float* __restrict__ ss) {
    int t = threadIdx.x;
    int w = t >> 6, l = t & 63;
    int o = blockIdx.x * 4 + w;
    float s1 = 0.f, s2 = 0.f;
    for (int i = l; i < NBLK_GS; i += 64) {
        const float* pb = psum + (size_t)i * 2 * C_OUT;
        s1 += pb[o];
        s2 += pb[C_OUT + o];
    }
#pragma unroll
    for (int d = 1; d < 64; d <<= 1) {
        s1 += __shfl_xor(s1, d, 64);
        s2 += __shfl_xor(s2, d, 64);
    }
    if (l == 0) {
        float mz = s1 / CNT_;
        float var = s2 / CNT_ - mz * mz;          // var(y) == var(z)
        float mean = mz + bias[o];
        float a = gamma[o] * rsqrtf(var + EPS_);
        ss[o] = a;
        // out = a*(z + bias - mean) + beta = a*z + (beta - a*mz)
        ss[C_OUT + o] = beta[o] - a * mz;
    }
}

// ---------------------------------------------------------------------------
// K5: GEMM (z = Wg) + out = a*z + shift. Same 2-half outer loop.
// ---------------------------------------------------------------------------
__global__ __launch_bounds__(256, 2) void k_final_gemm(const unsigned short* __restrict__ g,
                                                       const unsigned short* __restrict__ Wb,
                                                       const float* __restrict__ ss,
                                                       float* __restrict__ out) {
    int bid = blockIdx.x;
    int b  = bid / NB_N2;
    int nb = bid % NB_N2;
    int t = threadIdx.x;
    int w = t >> 6, l = t & 63, lr = l & 15, lg = l >> 4;
    int wbase = w * 64;

    bf16x8 afrag[4][4];
#pragma unroll
    for (int mt = 0; mt < 4; mt++)
#pragma unroll
        for (int ks = 0; ks < 4; ks++)
            afrag[mt][ks] = *reinterpret_cast<const bf16x8*>(
                Wb + (size_t)(wbase + mt * 16 + lr) * C_IN + ks * 32 + lg * 8);

    float sa[16], sh[16];
#pragma unroll
    for (int mt = 0; mt < 4; mt++)
#pragma unroll
        for (int j = 0; j < 4; j++) {
            int o = wbase + mt * 16 + lg * 4 + j;
            sa[mt * 4 + j] = ss[o];
            sh[mt * 4 + j] = ss[C_OUT + o];
        }

    const unsigned short* gb = g + (size_t)b * N_OUT * C_IN;
    float* ob = out + (size_t)b * C_OUT * N_OUT;

    for (int h = 0; h < 2; h++) {
        int n0 = nb * NT2 + h * 64;
        f32x4 acc[4][4];
#pragma unroll
        for (int mt = 0; mt < 4; mt++)
#pragma unroll
            for (int nt = 0; nt < 4; nt++) acc[mt][nt] = (f32x4)(0.0f);

#pragma unroll
        for (int nt = 0; nt < 4; nt++) {
            int n = n0 + nt * 16 + lr;
            const unsigned short* gr = gb + (size_t)((n < N_OUT) ? n : 0) * C_IN;
#pragma unroll
            for (int ks = 0; ks < 4; ks++) {
                bf16x8 bfr = *reinterpret_cast<const bf16x8*>(gr + ks * 32 + lg * 8);
#pragma unroll
                for (int mt = 0; mt < 4; mt++)
                    acc[mt][nt] = __builtin_amdgcn_mfma_f32_16x16x32_bf16(afrag[mt][ks], bfr,
                                                                         acc[mt][nt], 0, 0, 0);
            }
        }

#pragma unroll
        for (int mt = 0; mt < 4; mt++) {
#pragma unroll
            for (int j = 0; j < 4; j++) {
                int o = wbase + mt * 16 + lg * 4 + j;
                float a = sa[mt * 4 + j];
                float s = sh[mt * 4 + j];
#pragma unroll
                for (int nt = 0; nt < 4; nt++) {
                    int n = n0 + nt * 16 + lr;
                    if (n < N_OUT) ob[(size_t)o * N_OUT + n] = a * acc[mt][nt][j] + s;
                }
            }
        }
    }
}

// ---------------------------------------------------------------------------
extern "C" void kernel_launch(void* const* d_in, const int* in_sizes, int n_in,
                              void* d_out, int out_size, void* d_ws, size_t ws_size,
                              hipStream_t stream) {
    const float* x     = (const float*)d_in[0];
    const int*   idx   = (const int*)d_in[1];
    const float* W     = (const float*)d_in[2];
    const float* bias  = (const float*)d_in[3];
    const float* gamma = (const float*)d_in[4];
    const float* beta  = (const float*)d_in[5];
    float* out = (float*)d_out;

    const size_t xt_bytes = (size_t)B_ * N_IN * C_IN * sizeof(unsigned short);   // 41,945,088
    const size_t g_bytes  = (size_t)B_ * N_OUT * C_IN * sizeof(unsigned short);  // 10,487,808
    const size_t wb_bytes = (size_t)C_OUT * C_IN * sizeof(unsigned short);       // 65,536
    unsigned short* xT = (unsigned short*)d_ws;
    unsigned short* gg = (unsigned short*)((char*)d_ws + xt_bytes);
    unsigned short* Wb = (unsigned short*)((char*)d_ws + xt_bytes + g_bytes);
    float* psum = (float*)((char*)d_ws + xt_bytes + g_bytes + wb_bytes);         // 324*512*4 = 663 KB
    float* ss   = psum + (size_t)NBLK_GS * 2 * C_OUT;

    k_transpose<<<B_ * NB_I + WCONV_BLKS, 256, 0, stream>>>(x, xT, W, Wb);
    k_gather<<<B_ * NB_G, 256, 0, stream>>>(xT, idx, gg);
    k_stats_gemm<<<NBLK_GS, 256, 0, stream>>>(gg, Wb, psum);
    k_stats_final<<<64, 256, 0, stream>>>(psum, bias, gamma, beta, ss);
    k_final_gemm<<<B_ * NB_N2, 256, 0, stream>>>(gg, Wb, ss, out);
}